// Round 1
// baseline (306.888 us; speedup 1.0000x reference)
//
#include <hip/hip_runtime.h>

#define S_LEN 1024
#define D_DIM 128
#define QBLK 64
#define KVBLK 64

typedef __attribute__((ext_vector_type(8))) short short8;
typedef __attribute__((ext_vector_type(4))) short short4v;
typedef __attribute__((ext_vector_type(4))) float f32x4;

__device__ __forceinline__ unsigned short f2bf(float f) {
  union { float f; unsigned u; } x; x.f = f;
  unsigned r = x.u + 0x7fffu + ((x.u >> 16) & 1u);
  return (unsigned short)(r >> 16);
}

__device__ __forceinline__ short8 pack8(float4 a, float4 b) {
  short8 f;
  f[0] = (short)f2bf(a.x); f[1] = (short)f2bf(a.y);
  f[2] = (short)f2bf(a.z); f[3] = (short)f2bf(a.w);
  f[4] = (short)f2bf(b.x); f[5] = (short)f2bf(b.y);
  f[6] = (short)f2bf(b.z); f[7] = (short)f2bf(b.w);
  return f;
}

__global__ __launch_bounds__(256) void attn_fwd(
    const float* __restrict__ qg, const float* __restrict__ kg,
    const float* __restrict__ vg, float* __restrict__ og) {
  // K tile row-major [64][128] bf16, XOR-swizzled; V tile transposed [128][64]
  __shared__ unsigned short K_lds[KVBLK * D_DIM];
  __shared__ unsigned short VT_lds[D_DIM * KVBLK];
  __shared__ unsigned short P_lds[4][16 * KVBLK];  // per-wave P buffer

  const int tid = threadIdx.x;
  const int lane = tid & 63;
  const int wid = tid >> 6;
  const int l15 = lane & 15;
  const int lg = lane >> 4;

  // XCD-aware swizzle: all 16 q-tiles of one bh land on the same XCD
  const int bid = blockIdx.x;
  const int bh = (bid & 7) | ((bid >> 7) << 3);
  const int qt = (bid >> 3) & 15;

  const size_t base = (size_t)bh * (S_LEN * D_DIM);
  const int qw = qt * QBLK + wid * 16;  // wave's first q row

  // ---- Q fragments in registers, pre-scaled by 1/128 (exact in bf16) ----
  short8 qf[4];
  {
    const float* qp = qg + base + (size_t)(qw + l15) * D_DIM + lg * 8;
    #pragma unroll
    for (int c = 0; c < 4; ++c) {
      float4 a = *(const float4*)(qp + c * 32);
      float4 b = *(const float4*)(qp + c * 32 + 4);
      const float s = 0.0078125f;
      a.x *= s; a.y *= s; a.z *= s; a.w *= s;
      b.x *= s; b.y *= s; b.z *= s; b.w *= s;
      qf[c] = pack8(a, b);
    }
  }

  float m_r[4], l_r[4];
  f32x4 o_acc[8];
  #pragma unroll
  for (int r = 0; r < 4; ++r) { m_r[r] = -INFINITY; l_r[r] = 0.f; }
  #pragma unroll
  for (int dt = 0; dt < 8; ++dt) o_acc[dt] = (f32x4){0.f, 0.f, 0.f, 0.f};

  for (int kv0 = 0; kv0 < S_LEN; kv0 += KVBLK) {
    // ---- stage K tile -> bf16 LDS, swizzled ----
    {
      const float* kb = kg + base + (size_t)kv0 * D_DIM;
      #pragma unroll
      for (int c = tid; c < KVBLK * D_DIM / 8; c += 256) {
        int row = c >> 4, dc = c & 15;
        const float* p = kb + row * D_DIM + dc * 8;
        float4 a = *(const float4*)p;
        float4 b = *(const float4*)(p + 4);
        int sidx = row * 128 + ((dc * 8) ^ ((row & 7) << 3));
        *(short8*)&K_lds[sidx] = pack8(a, b);
      }
    }
    // ---- stage V^T tile: 4x4 register transpose blocks ----
    {
      const float* vb = vg + base + (size_t)kv0 * D_DIM;
      #pragma unroll
      for (int u = tid; u < (KVBLK / 4) * (D_DIM / 4); u += 256) {
        int ib = u & 15;        // i block (4 rows of V)
        int db = u >> 4;        // d block (4 cols of V)
        const float* p = vb + (ib * 4) * D_DIM + db * 4;
        float rr[4][4];
        #pragma unroll
        for (int c = 0; c < 4; ++c) {
          float4 t = *(const float4*)(p + c * D_DIM);
          rr[c][0] = t.x; rr[c][1] = t.y; rr[c][2] = t.z; rr[c][3] = t.w;
        }
        #pragma unroll
        for (int j = 0; j < 4; ++j) {
          short4v w;
          w[0] = (short)f2bf(rr[0][j]); w[1] = (short)f2bf(rr[1][j]);
          w[2] = (short)f2bf(rr[2][j]); w[3] = (short)f2bf(rr[3][j]);
          int row = db * 4 + j;  // d index
          int sidx = row * 64 + ((ib * 4) ^ ((row & 7) << 3));
          *(short4v*)&VT_lds[sidx] = w;
        }
      }
    }
    __syncthreads();

    // ---- QK^T: 4 col-tiles x 4 d-chunks ----
    f32x4 sacc[4];
    #pragma unroll
    for (int tc = 0; tc < 4; ++tc) sacc[tc] = (f32x4){0.f, 0.f, 0.f, 0.f};
    #pragma unroll
    for (int tc = 0; tc < 4; ++tc) {
      int row = tc * 16 + l15;
      #pragma unroll
      for (int ck = 0; ck < 4; ++ck) {
        int sidx = row * 128 + ((ck * 32 + lg * 8) ^ ((row & 7) << 3));
        short8 kf = *(const short8*)&K_lds[sidx];
        sacc[tc] = __builtin_amdgcn_mfma_f32_16x16x32_bf16(qf[ck], kf, sacc[tc], 0, 0, 0);
      }
    }

    // ---- online softmax (4 rows per lane-group handled via the 4 acc regs) ----
    float alpha[4], ps[4];
    #pragma unroll
    for (int r = 0; r < 4; ++r) {
      float a = fmaxf(fmaxf(sacc[0][r], sacc[1][r]), fmaxf(sacc[2][r], sacc[3][r]));
      a = fmaxf(a, __shfl_xor(a, 1));
      a = fmaxf(a, __shfl_xor(a, 2));
      a = fmaxf(a, __shfl_xor(a, 4));
      a = fmaxf(a, __shfl_xor(a, 8));
      float mn = fmaxf(m_r[r], a);
      alpha[r] = __expf(m_r[r] - mn);
      m_r[r] = mn;
      ps[r] = 0.f;
    }
    #pragma unroll
    for (int tc = 0; tc < 4; ++tc) {
      #pragma unroll
      for (int r = 0; r < 4; ++r) {
        float p = __expf(sacc[tc][r] - m_r[r]);
        ps[r] += p;
        int prow = lg * 4 + r;
        int pcol = tc * 16 + l15;
        P_lds[wid][prow * 64 + (pcol ^ ((prow & 7) << 3))] = f2bf(p);
      }
    }
    #pragma unroll
    for (int r = 0; r < 4; ++r) {
      float s = ps[r];
      s += __shfl_xor(s, 1); s += __shfl_xor(s, 2);
      s += __shfl_xor(s, 4); s += __shfl_xor(s, 8);
      l_r[r] = l_r[r] * alpha[r] + s;
    }
    #pragma unroll
    for (int dt = 0; dt < 8; ++dt) {
      #pragma unroll
      for (int r = 0; r < 4; ++r) o_acc[dt][r] *= alpha[r];
    }

    // ---- PV: out[16][128] += P[16][64] * V[64][128] ----
    #pragma unroll
    for (int kc = 0; kc < 2; ++kc) {
      int pidx = l15 * 64 + ((kc * 32 + lg * 8) ^ ((l15 & 7) << 3));
      short8 pf = *(const short8*)&P_lds[wid][pidx];
      #pragma unroll
      for (int dt = 0; dt < 8; ++dt) {
        int vrow = dt * 16 + l15;
        int vidx = vrow * 64 + ((kc * 32 + lg * 8) ^ ((vrow & 7) << 3));
        short8 vf = *(const short8*)&VT_lds[vidx];
        o_acc[dt] = __builtin_amdgcn_mfma_f32_16x16x32_bf16(pf, vf, o_acc[dt], 0, 0, 0);
      }
    }
    __syncthreads();
  }

  // ---- epilogue: out = o_acc / l ----
  #pragma unroll
  for (int r = 0; r < 4; ++r) {
    float inv = 1.0f / l_r[r];
    float* op = og + base + (size_t)(qw + lg * 4 + r) * D_DIM + l15;
    #pragma unroll
    for (int dt = 0; dt < 8; ++dt) op[dt * 16] = o_acc[dt][r] * inv;
  }
}

extern "C" void kernel_launch(void* const* d_in, const int* in_sizes, int n_in,
                              void* d_out, int out_size, void* d_ws, size_t ws_size,
                              hipStream_t stream) {
  const float* q = (const float*)d_in[0];
  const float* k = (const float*)d_in[1];
  const float* v = (const float*)d_in[2];
  float* o = (float*)d_out;
  attn_fwd<<<dim3(2048), dim3(256), 0, stream>>>(q, k, v, o);
}

// Round 2
// 216.018 us; speedup vs baseline: 1.4207x; 1.4207x over previous
//
#include <hip/hip_runtime.h>

#define S_LEN 1024
#define D_DIM 128
#define QBLK 64
#define KVBLK 64
#define BH_N 128

typedef __attribute__((ext_vector_type(8))) short short8;
typedef __attribute__((ext_vector_type(4))) short short4v;
typedef __attribute__((ext_vector_type(4))) float f32x4;

__device__ __forceinline__ unsigned short f2bf(float f) {
  union { float f; unsigned u; } x; x.f = f;
  unsigned r = x.u + 0x7fffu + ((x.u >> 16) & 1u);
  return (unsigned short)(r >> 16);
}

__device__ __forceinline__ short8 pack8(float4 a, float4 b) {
  short8 f;
  f[0] = (short)f2bf(a.x); f[1] = (short)f2bf(a.y);
  f[2] = (short)f2bf(a.z); f[3] = (short)f2bf(a.w);
  f[4] = (short)f2bf(b.x); f[5] = (short)f2bf(b.y);
  f[6] = (short)f2bf(b.z); f[7] = (short)f2bf(b.w);
  return f;
}

__device__ __forceinline__ void gload_lds16(const void* g, void* l) {
  __builtin_amdgcn_global_load_lds(
      (const __attribute__((address_space(1))) unsigned int*)g,
      (__attribute__((address_space(3))) unsigned int*)l, 16, 0, 0);
}

// ---------- prepass 1: K f32 -> bf16 row-major ----------
__global__ __launch_bounds__(256) void conv_k(const float* __restrict__ in,
                                              unsigned short* __restrict__ out,
                                              int n8) {
  int i = blockIdx.x * 256 + threadIdx.x;
  int stride = gridDim.x * 256;
  for (; i < n8; i += stride) {
    float4 a = ((const float4*)in)[i * 2];
    float4 b = ((const float4*)in)[i * 2 + 1];
    ((short8*)out)[i] = pack8(a, b);
  }
}

// ---------- prepass 2: V f32 [bh][s][d] -> bf16 VT [bh][d][s] ----------
__global__ __launch_bounds__(256) void conv_vt(const float* __restrict__ v,
                                               unsigned short* __restrict__ vt) {
  __shared__ unsigned short tile[64][72];
  int b = blockIdx.x;                 // 128 bh * 16 s-tiles * 2 d-tiles = 4096
  int d0 = (b & 1) * 64;
  int s0 = ((b >> 1) & 15) * 64;
  int bh = b >> 5;
  int t = threadIdx.x;
  #pragma unroll
  for (int i = 0; i < 4; ++i) {
    int s = (t >> 4) + i * 16;
    int dl = (t & 15) * 4;
    float4 x = *(const float4*)(v + ((size_t)(bh * S_LEN) + s0 + s) * D_DIM + d0 + dl);
    tile[s][dl + 0] = f2bf(x.x); tile[s][dl + 1] = f2bf(x.y);
    tile[s][dl + 2] = f2bf(x.z); tile[s][dl + 3] = f2bf(x.w);
  }
  __syncthreads();
  #pragma unroll
  for (int i = 0; i < 2; ++i) {
    int j = i * 256 + t;
    int dl = j >> 3, sc = j & 7;
    short8 w;
    #pragma unroll
    for (int q = 0; q < 8; ++q) w[q] = (short)tile[sc * 8 + q][dl];
    *(short8*)(vt + ((size_t)(bh * D_DIM) + d0 + dl) * S_LEN + s0 + sc * 8) = w;
  }
}

// ---------- main attention: bf16 K/VT from ws, dbuf global_load_lds ----------
__global__ __launch_bounds__(256) void attn_main(
    const float* __restrict__ qg, const unsigned short* __restrict__ kbf,
    const unsigned short* __restrict__ vtbf, float* __restrict__ og) {
  __shared__ unsigned short K_lds[2][KVBLK * D_DIM];   // 2 x 16 KB
  __shared__ unsigned short VT_lds[2][D_DIM * KVBLK];  // 2 x 16 KB
  __shared__ unsigned short P_lds[4][16 * KVBLK];      // 8 KB

  const int tid = threadIdx.x;
  const int lane = tid & 63;
  const int wid = tid >> 6;
  const int l15 = lane & 15;
  const int lg = lane >> 4;

  const int bid = blockIdx.x;
  const int bh = (bid & 7) | ((bid >> 7) << 3);  // same-bh blocks share XCD
  const int qt = (bid >> 3) & 15;

  const size_t base = (size_t)bh * (S_LEN * D_DIM);
  const int qw = qt * QBLK + wid * 16;

  // Q fragments, pre-scaled by 1/128 (exact in bf16)
  short8 qf[4];
  {
    const float* qp = qg + base + (size_t)(qw + l15) * D_DIM + lg * 8;
    #pragma unroll
    for (int c = 0; c < 4; ++c) {
      float4 a = *(const float4*)(qp + c * 32);
      float4 b = *(const float4*)(qp + c * 32 + 4);
      const float s = 0.0078125f;
      a.x *= s; a.y *= s; a.z *= s; a.w *= s;
      b.x *= s; b.y *= s; b.z *= s; b.w *= s;
      qf[c] = pack8(a, b);
    }
  }

  float m_r[4], l_r[4];
  f32x4 o_acc[8];
  #pragma unroll
  for (int r = 0; r < 4; ++r) { m_r[r] = -INFINITY; l_r[r] = 0.f; }
  #pragma unroll
  for (int dt = 0; dt < 8; ++dt) o_acc[dt] = (f32x4){0.f, 0.f, 0.f, 0.f};

  const unsigned short* kb = kbf + (size_t)bh * (S_LEN * D_DIM);
  const unsigned short* vtb = vtbf + (size_t)bh * (D_DIM * S_LEN);

  // stage tile kv0 into buffer `buf` (per-wave: 4 K-loads + 4 VT-loads)
  #define STAGE(buf, kv0)                                                        \
    {                                                                            \
      _Pragma("unroll")                                                          \
      for (int i = 0; i < 4; ++i) {                                              \
        int row = wid * 16 + i * 4 + (lane >> 4);                                \
        int c = lane & 15;                                                       \
        const unsigned short* src =                                              \
            kb + (size_t)((kv0) + row) * D_DIM + ((c ^ (row & 7)) * 8);          \
        gload_lds16(src, &K_lds[buf][(wid * 16 + i * 4) * D_DIM]);               \
      }                                                                          \
      _Pragma("unroll")                                                          \
      for (int i = 0; i < 4; ++i) {                                              \
        int drow = (wid * 4 + i) * 8 + (lane >> 3);                              \
        int c = lane & 7;                                                        \
        const unsigned short* src =                                              \
            vtb + (size_t)drow * S_LEN + (kv0) + ((c ^ (drow & 7)) * 8);         \
        gload_lds16(src, &VT_lds[buf][(wid * 4 + i) * 8 * KVBLK]);               \
      }                                                                          \
    }

  STAGE(0, 0);
  __syncthreads();

  int cur = 0;
  for (int t = 0; t < S_LEN / KVBLK; ++t) {
    if (t + 1 < S_LEN / KVBLK) STAGE(cur ^ 1, (t + 1) * KVBLK);

    // ---- QK^T ----
    f32x4 sacc[4];
    #pragma unroll
    for (int tc = 0; tc < 4; ++tc) sacc[tc] = (f32x4){0.f, 0.f, 0.f, 0.f};
    #pragma unroll
    for (int tc = 0; tc < 4; ++tc) {
      int row = tc * 16 + l15;
      #pragma unroll
      for (int ck = 0; ck < 4; ++ck) {
        int sidx = row * 128 + ((ck * 32 + lg * 8) ^ ((row & 7) << 3));
        short8 kf = *(const short8*)&K_lds[cur][sidx];
        sacc[tc] = __builtin_amdgcn_mfma_f32_16x16x32_bf16(qf[ck], kf, sacc[tc], 0, 0, 0);
      }
    }

    // ---- online softmax ----
    float alpha[4], ps[4];
    #pragma unroll
    for (int r = 0; r < 4; ++r) {
      float a = fmaxf(fmaxf(sacc[0][r], sacc[1][r]), fmaxf(sacc[2][r], sacc[3][r]));
      a = fmaxf(a, __shfl_xor(a, 1));
      a = fmaxf(a, __shfl_xor(a, 2));
      a = fmaxf(a, __shfl_xor(a, 4));
      a = fmaxf(a, __shfl_xor(a, 8));
      float mn = fmaxf(m_r[r], a);
      alpha[r] = __expf(m_r[r] - mn);
      m_r[r] = mn;
      ps[r] = 0.f;
    }
    #pragma unroll
    for (int tc = 0; tc < 4; ++tc) {
      #pragma unroll
      for (int r = 0; r < 4; ++r) {
        float p = __expf(sacc[tc][r] - m_r[r]);
        ps[r] += p;
        int prow = lg * 4 + r;
        int pcol = tc * 16 + l15;
        P_lds[wid][prow * 64 + (pcol ^ ((prow & 7) << 3))] = f2bf(p);
      }
    }
    #pragma unroll
    for (int r = 0; r < 4; ++r) {
      float s = ps[r];
      s += __shfl_xor(s, 1); s += __shfl_xor(s, 2);
      s += __shfl_xor(s, 4); s += __shfl_xor(s, 8);
      l_r[r] = l_r[r] * alpha[r] + s;
    }
    #pragma unroll
    for (int dt = 0; dt < 8; ++dt) {
      #pragma unroll
      for (int r = 0; r < 4; ++r) o_acc[dt][r] *= alpha[r];
    }

    // ---- PV ----
    #pragma unroll
    for (int kc = 0; kc < 2; ++kc) {
      int pidx = l15 * 64 + ((kc * 32 + lg * 8) ^ ((l15 & 7) << 3));
      short8 pf = *(const short8*)&P_lds[wid][pidx];
      #pragma unroll
      for (int dt = 0; dt < 8; ++dt) {
        int vrow = dt * 16 + l15;
        int vidx = vrow * 64 + ((kc * 32 + lg * 8) ^ ((vrow & 7) << 3));
        short8 vf = *(const short8*)&VT_lds[cur][vidx];
        o_acc[dt] = __builtin_amdgcn_mfma_f32_16x16x32_bf16(pf, vf, o_acc[dt], 0, 0, 0);
      }
    }
    __syncthreads();  // drains vmcnt for the staged loads too
    cur ^= 1;
  }

  #pragma unroll
  for (int r = 0; r < 4; ++r) {
    float inv = 1.0f / l_r[r];
    float* op = og + base + (size_t)(qw + lg * 4 + r) * D_DIM + l15;
    #pragma unroll
    for (int dt = 0; dt < 8; ++dt) op[dt * 16] = o_acc[dt][r] * inv;
  }
}

// ---------- fallback (round-1 fused kernel) if ws too small ----------
__global__ __launch_bounds__(256) void attn_fused(
    const float* __restrict__ qg, const float* __restrict__ kg,
    const float* __restrict__ vg, float* __restrict__ og) {
  __shared__ unsigned short K_lds[KVBLK * D_DIM];
  __shared__ unsigned short VT_lds[D_DIM * KVBLK];
  __shared__ unsigned short P_lds[4][16 * KVBLK];

  const int tid = threadIdx.x;
  const int lane = tid & 63;
  const int wid = tid >> 6;
  const int l15 = lane & 15;
  const int lg = lane >> 4;

  const int bid = blockIdx.x;
  const int bh = (bid & 7) | ((bid >> 7) << 3);
  const int qt = (bid >> 3) & 15;

  const size_t base = (size_t)bh * (S_LEN * D_DIM);
  const int qw = qt * QBLK + wid * 16;

  short8 qf[4];
  {
    const float* qp = qg + base + (size_t)(qw + l15) * D_DIM + lg * 8;
    #pragma unroll
    for (int c = 0; c < 4; ++c) {
      float4 a = *(const float4*)(qp + c * 32);
      float4 b = *(const float4*)(qp + c * 32 + 4);
      const float s = 0.0078125f;
      a.x *= s; a.y *= s; a.z *= s; a.w *= s;
      b.x *= s; b.y *= s; b.z *= s; b.w *= s;
      qf[c] = pack8(a, b);
    }
  }

  float m_r[4], l_r[4];
  f32x4 o_acc[8];
  #pragma unroll
  for (int r = 0; r < 4; ++r) { m_r[r] = -INFINITY; l_r[r] = 0.f; }
  #pragma unroll
  for (int dt = 0; dt < 8; ++dt) o_acc[dt] = (f32x4){0.f, 0.f, 0.f, 0.f};

  for (int kv0 = 0; kv0 < S_LEN; kv0 += KVBLK) {
    {
      const float* kb = kg + base + (size_t)kv0 * D_DIM;
      #pragma unroll
      for (int c = tid; c < KVBLK * D_DIM / 8; c += 256) {
        int row = c >> 4, dc = c & 15;
        const float* p = kb + row * D_DIM + dc * 8;
        float4 a = *(const float4*)p;
        float4 b = *(const float4*)(p + 4);
        int sidx = row * 128 + ((dc * 8) ^ ((row & 7) << 3));
        *(short8*)&K_lds[sidx] = pack8(a, b);
      }
    }
    {
      const float* vb = vg + base + (size_t)kv0 * D_DIM;
      #pragma unroll
      for (int u = tid; u < (KVBLK / 4) * (D_DIM / 4); u += 256) {
        int ib = u & 15;
        int db = u >> 4;
        const float* p = vb + (ib * 4) * D_DIM + db * 4;
        float rr[4][4];
        #pragma unroll
        for (int c = 0; c < 4; ++c) {
          float4 t = *(const float4*)(p + c * D_DIM);
          rr[c][0] = t.x; rr[c][1] = t.y; rr[c][2] = t.z; rr[c][3] = t.w;
        }
        #pragma unroll
        for (int j = 0; j < 4; ++j) {
          short4v w;
          w[0] = (short)f2bf(rr[0][j]); w[1] = (short)f2bf(rr[1][j]);
          w[2] = (short)f2bf(rr[2][j]); w[3] = (short)f2bf(rr[3][j]);
          int row = db * 4 + j;
          int sidx = row * 64 + ((ib * 4) ^ ((row & 7) << 3));
          *(short4v*)&VT_lds[sidx] = w;
        }
      }
    }
    __syncthreads();

    f32x4 sacc[4];
    #pragma unroll
    for (int tc = 0; tc < 4; ++tc) sacc[tc] = (f32x4){0.f, 0.f, 0.f, 0.f};
    #pragma unroll
    for (int tc = 0; tc < 4; ++tc) {
      int row = tc * 16 + l15;
      #pragma unroll
      for (int ck = 0; ck < 4; ++ck) {
        int sidx = row * 128 + ((ck * 32 + lg * 8) ^ ((row & 7) << 3));
        short8 kf = *(const short8*)&K_lds[sidx];
        sacc[tc] = __builtin_amdgcn_mfma_f32_16x16x32_bf16(qf[ck], kf, sacc[tc], 0, 0, 0);
      }
    }

    float alpha[4], ps[4];
    #pragma unroll
    for (int r = 0; r < 4; ++r) {
      float a = fmaxf(fmaxf(sacc[0][r], sacc[1][r]), fmaxf(sacc[2][r], sacc[3][r]));
      a = fmaxf(a, __shfl_xor(a, 1));
      a = fmaxf(a, __shfl_xor(a, 2));
      a = fmaxf(a, __shfl_xor(a, 4));
      a = fmaxf(a, __shfl_xor(a, 8));
      float mn = fmaxf(m_r[r], a);
      alpha[r] = __expf(m_r[r] - mn);
      m_r[r] = mn;
      ps[r] = 0.f;
    }
    #pragma unroll
    for (int tc = 0; tc < 4; ++tc) {
      #pragma unroll
      for (int r = 0; r < 4; ++r) {
        float p = __expf(sacc[tc][r] - m_r[r]);
        ps[r] += p;
        int prow = lg * 4 + r;
        int pcol = tc * 16 + l15;
        P_lds[wid][prow * 64 + (pcol ^ ((prow & 7) << 3))] = f2bf(p);
      }
    }
    #pragma unroll
    for (int r = 0; r < 4; ++r) {
      float s = ps[r];
      s += __shfl_xor(s, 1); s += __shfl_xor(s, 2);
      s += __shfl_xor(s, 4); s += __shfl_xor(s, 8);
      l_r[r] = l_r[r] * alpha[r] + s;
    }
    #pragma unroll
    for (int dt = 0; dt < 8; ++dt) {
      #pragma unroll
      for (int r = 0; r < 4; ++r) o_acc[dt][r] *= alpha[r];
    }

    #pragma unroll
    for (int kc = 0; kc < 2; ++kc) {
      int pidx = l15 * 64 + ((kc * 32 + lg * 8) ^ ((l15 & 7) << 3));
      short8 pf = *(const short8*)&P_lds[wid][pidx];
      #pragma unroll
      for (int dt = 0; dt < 8; ++dt) {
        int vrow = dt * 16 + l15;
        int vidx = vrow * 64 + ((kc * 32 + lg * 8) ^ ((vrow & 7) << 3));
        short8 vf = *(const short8*)&VT_lds[vidx];
        o_acc[dt] = __builtin_amdgcn_mfma_f32_16x16x32_bf16(pf, vf, o_acc[dt], 0, 0, 0);
      }
    }
    __syncthreads();
  }

  #pragma unroll
  for (int r = 0; r < 4; ++r) {
    float inv = 1.0f / l_r[r];
    float* op = og + base + (size_t)(qw + lg * 4 + r) * D_DIM + l15;
    #pragma unroll
    for (int dt = 0; dt < 8; ++dt) op[dt * 16] = o_acc[dt][r] * inv;
  }
}

extern "C" void kernel_launch(void* const* d_in, const int* in_sizes, int n_in,
                              void* d_out, int out_size, void* d_ws, size_t ws_size,
                              hipStream_t stream) {
  const float* q = (const float*)d_in[0];
  const float* k = (const float*)d_in[1];
  const float* v = (const float*)d_in[2];
  float* o = (float*)d_out;

  const size_t n_elem = (size_t)BH_N * S_LEN * D_DIM;  // 16.78M
  const size_t need = 2 * n_elem * sizeof(unsigned short);

  if (ws_size >= need) {
    unsigned short* kbf = (unsigned short*)d_ws;
    unsigned short* vtbf = kbf + n_elem;
    conv_k<<<dim3(2048), dim3(256), 0, stream>>>(k, kbf, (int)(n_elem / 8));
    conv_vt<<<dim3(4096), dim3(256), 0, stream>>>(v, vtbf);
    attn_main<<<dim3(2048), dim3(256), 0, stream>>>(q, kbf, vtbf, o);
  } else {
    attn_fused<<<dim3(2048), dim3(256), 0, stream>>>(q, k, v, o);
  }
}

// Round 3
// 155.181 us; speedup vs baseline: 1.9776x; 1.3920x over previous
//
#include <hip/hip_runtime.h>

#define S_LEN 1024
#define D_DIM 128
#define KVBLK 64
#define QROWS_BLK 128  // 8 waves * 16 q-rows
#define BH_N 128
#define M0_LOG2 2.0f   // fixed softmax base (log2 domain); scores*log2e stay < 1

typedef __attribute__((ext_vector_type(8))) short short8;
typedef __attribute__((ext_vector_type(4))) short short4v;
typedef __attribute__((ext_vector_type(4))) float f32x4;

__device__ __forceinline__ unsigned short f2bf(float f) {
  union { float f; unsigned u; } x; x.f = f;
  unsigned r = x.u + 0x7fffu + ((x.u >> 16) & 1u);
  return (unsigned short)(r >> 16);
}

__device__ __forceinline__ short8 pack8(float4 a, float4 b) {
  short8 f;
  f[0] = (short)f2bf(a.x); f[1] = (short)f2bf(a.y);
  f[2] = (short)f2bf(a.z); f[3] = (short)f2bf(a.w);
  f[4] = (short)f2bf(b.x); f[5] = (short)f2bf(b.y);
  f[6] = (short)f2bf(b.z); f[7] = (short)f2bf(b.w);
  return f;
}

__device__ __forceinline__ void gload_lds16(const void* g, void* l) {
  __builtin_amdgcn_global_load_lds(
      (const __attribute__((address_space(1))) unsigned int*)g,
      (__attribute__((address_space(3))) unsigned int*)l, 16, 0, 0);
}

// ---------- prepass 1: K f32 -> bf16 row-major ----------
__global__ __launch_bounds__(256) void conv_k(const float* __restrict__ in,
                                              unsigned short* __restrict__ out,
                                              int n8) {
  int i = blockIdx.x * 256 + threadIdx.x;
  int stride = gridDim.x * 256;
  for (; i < n8; i += stride) {
    float4 a = ((const float4*)in)[i * 2];
    float4 b = ((const float4*)in)[i * 2 + 1];
    ((short8*)out)[i] = pack8(a, b);
  }
}

// ---------- prepass 2: V f32 [bh][s][d] -> bf16 VT [bh][d][s] ----------
__global__ __launch_bounds__(256) void conv_vt(const float* __restrict__ v,
                                               unsigned short* __restrict__ vt) {
  __shared__ unsigned short tile[64][72];
  int b = blockIdx.x;  // 128 bh * 16 s-tiles * 2 d-tiles = 4096
  int d0 = (b & 1) * 64;
  int s0 = ((b >> 1) & 15) * 64;
  int bh = b >> 5;
  int t = threadIdx.x;
  #pragma unroll
  for (int i = 0; i < 4; ++i) {
    int s = (t >> 4) + i * 16;
    int dl = (t & 15) * 4;
    float4 x = *(const float4*)(v + ((size_t)(bh * S_LEN) + s0 + s) * D_DIM + d0 + dl);
    tile[s][dl + 0] = f2bf(x.x); tile[s][dl + 1] = f2bf(x.y);
    tile[s][dl + 2] = f2bf(x.z); tile[s][dl + 3] = f2bf(x.w);
  }
  __syncthreads();
  #pragma unroll
  for (int i = 0; i < 2; ++i) {
    int j = i * 256 + t;
    int dl = j >> 3, sc = j & 7;
    short8 w;
    #pragma unroll
    for (int q = 0; q < 8; ++q) w[q] = (short)tile[sc * 8 + q][dl];
    *(short8*)(vt + ((size_t)(bh * D_DIM) + d0 + dl) * S_LEN + s0 + sc * 8) = w;
  }
}

// ---------- main attention ----------
__global__ __launch_bounds__(512, 4) void attn_main(
    const float* __restrict__ qg, const unsigned short* __restrict__ kbf,
    const unsigned short* __restrict__ vtbf, float* __restrict__ og) {
  __shared__ unsigned short K_lds[2][KVBLK * D_DIM];   // 2 x 16 KB
  __shared__ unsigned short VT_lds[2][D_DIM * KVBLK];  // 2 x 16 KB
  __shared__ unsigned short P_lds[8][16 * KVBLK];      // 16 KB

  const int tid = threadIdx.x;
  const int lane = tid & 63;
  const int wid = tid >> 6;
  const int l15 = lane & 15;
  const int lg = lane >> 4;

  // XCD swizzle: each XCD walks one bh's 8 q-tiles at a time -> K/V L2-resident
  const int bid = blockIdx.x;
  const int bh = (bid & 7) | ((bid >> 6) << 3);
  const int qt = (bid >> 3) & 7;

  const size_t base = (size_t)bh * (S_LEN * D_DIM);
  const int qw = qt * QROWS_BLK + wid * 16;

  // Q fragments, pre-scaled by log2(e)/128 (scores land in exp2 domain)
  short8 qf[4];
  {
    const float* qp = qg + base + (size_t)(qw + l15) * D_DIM + lg * 8;
    const float s = 0.0078125f * 1.44269504088896f;
    #pragma unroll
    for (int c = 0; c < 4; ++c) {
      float4 a = *(const float4*)(qp + c * 32);
      float4 b = *(const float4*)(qp + c * 32 + 4);
      a.x *= s; a.y *= s; a.z *= s; a.w *= s;
      b.x *= s; b.y *= s; b.z *= s; b.w *= s;
      qf[c] = pack8(a, b);
    }
  }

  float neg_m[4];  // -m per row (log2 domain); folded into MFMA acc init
  float l_r[4];
  f32x4 o_acc[8];
  #pragma unroll
  for (int r = 0; r < 4; ++r) { neg_m[r] = -M0_LOG2; l_r[r] = 0.f; }
  #pragma unroll
  for (int dt = 0; dt < 8; ++dt) o_acc[dt] = (f32x4){0.f, 0.f, 0.f, 0.f};

  const unsigned short* kb = kbf + (size_t)bh * (S_LEN * D_DIM);
  const unsigned short* vtb = vtbf + (size_t)bh * (D_DIM * S_LEN);

  // per-wave staging: K rows [wid*8, wid*8+8), VT d-rows [wid*16, wid*16+16)
  #define STAGE(buf, kv0)                                                      \
    {                                                                          \
      _Pragma("unroll")                                                        \
      for (int i = 0; i < 2; ++i) {                                            \
        int row = wid * 8 + i * 4 + (lane >> 4);                               \
        int c = lane & 15;                                                     \
        const unsigned short* src =                                            \
            kb + (size_t)((kv0) + row) * D_DIM + ((c ^ (row & 7)) * 8);        \
        gload_lds16(src, &K_lds[buf][(wid * 8 + i * 4) * D_DIM]);              \
      }                                                                        \
      _Pragma("unroll")                                                        \
      for (int i = 0; i < 2; ++i) {                                            \
        int drow = wid * 16 + i * 8 + (lane >> 3);                             \
        int c = lane & 7;                                                      \
        const unsigned short* src =                                            \
            vtb + (size_t)drow * S_LEN + (kv0) + ((c ^ (drow & 7)) * 8);       \
        gload_lds16(src, &VT_lds[buf][(wid * 16 + i * 8) * KVBLK]);            \
      }                                                                        \
    }

  STAGE(0, 0);
  __syncthreads();

  #pragma unroll 2
  for (int t = 0; t < S_LEN / KVBLK; ++t) {
    const int cur = t & 1;
    if (t + 1 < S_LEN / KVBLK) STAGE(cur ^ 1, (t + 1) * KVBLK);

    // ---- QK^T with accumulator pre-loaded to -m (p = exp2(sacc) directly) ----
    f32x4 nm = (f32x4){neg_m[0], neg_m[1], neg_m[2], neg_m[3]};
    f32x4 sacc[4];
    #pragma unroll
    for (int tc = 0; tc < 4; ++tc) sacc[tc] = nm;
    #pragma unroll
    for (int tc = 0; tc < 4; ++tc) {
      int row = tc * 16 + l15;
      #pragma unroll
      for (int ck = 0; ck < 4; ++ck) {
        int sidx = row * 128 + ((ck * 32 + lg * 8) ^ ((row & 7) << 3));
        short8 kf = *(const short8*)&K_lds[cur][sidx];
        sacc[tc] = __builtin_amdgcn_mfma_f32_16x16x32_bf16(qf[ck], kf, sacc[tc], 0, 0, 0);
      }
    }

    // ---- guard: escalate to full online softmax if any score exceeds m ----
    float lmax = sacc[0][0];
    #pragma unroll
    for (int tc = 0; tc < 4; ++tc) {
      #pragma unroll
      for (int r = 0; r < 4; ++r) lmax = fmaxf(lmax, sacc[tc][r]);
    }
    if (__any(lmax > 0.f)) {  // never taken for bounded scores; exact fallback
      #pragma unroll
      for (int r = 0; r < 4; ++r) {
        float a = fmaxf(fmaxf(sacc[0][r], sacc[1][r]), fmaxf(sacc[2][r], sacc[3][r]));
        a = fmaxf(a, __shfl_xor(a, 1));
        a = fmaxf(a, __shfl_xor(a, 2));
        a = fmaxf(a, __shfl_xor(a, 4));
        a = fmaxf(a, __shfl_xor(a, 8));
        float g = fmaxf(a, 0.f);          // m grows by g
        float alpha = exp2f(-g);
        neg_m[r] -= g;
        l_r[r] *= alpha;
        #pragma unroll
        for (int dt = 0; dt < 8; ++dt) o_acc[dt][r] *= alpha;
        #pragma unroll
        for (int tc = 0; tc < 4; ++tc) sacc[tc][r] -= g;
      }
    }

    // ---- p = exp2(sacc); accumulate l; write P (bank-spread swizzle) ----
    #pragma unroll
    for (int tc = 0; tc < 4; ++tc) {
      #pragma unroll
      for (int r = 0; r < 4; ++r) {
        float p = exp2f(sacc[tc][r]);
        l_r[r] += p;
        int prow = lg * 4 + r;
        int pcol = tc * 16 + l15;
        P_lds[wid][prow * 64 + (pcol ^ (((prow >> 2) & 3) << 4))] = f2bf(p);
      }
    }

    // ---- PV ----
    #pragma unroll
    for (int kc = 0; kc < 2; ++kc) {
      int pidx = l15 * 64 + ((kc * 32 + lg * 8) ^ (((l15 >> 2) & 3) << 4));
      short8 pf = *(const short8*)&P_lds[wid][pidx];
      #pragma unroll
      for (int dt = 0; dt < 8; ++dt) {
        int vrow = dt * 16 + l15;
        int vidx = vrow * 64 + ((kc * 32 + lg * 8) ^ ((vrow & 7) << 3));
        short8 vf = *(const short8*)&VT_lds[cur][vidx];
        o_acc[dt] = __builtin_amdgcn_mfma_f32_16x16x32_bf16(pf, vf, o_acc[dt], 0, 0, 0);
      }
    }
    __syncthreads();
  }

  // ---- deferred l reduction + epilogue ----
  float linv[4];
  #pragma unroll
  for (int r = 0; r < 4; ++r) {
    float s = l_r[r];
    s += __shfl_xor(s, 1); s += __shfl_xor(s, 2);
    s += __shfl_xor(s, 4); s += __shfl_xor(s, 8);
    linv[r] = 1.0f / s;
  }
  #pragma unroll
  for (int r = 0; r < 4; ++r) {
    float* op = og + base + (size_t)(qw + lg * 4 + r) * D_DIM + l15;
    #pragma unroll
    for (int dt = 0; dt < 8; ++dt) op[dt * 16] = o_acc[dt][r] * linv[r];
  }
}

// ---------- fallback (fused, f32 inputs) if ws too small ----------
__global__ __launch_bounds__(256) void attn_fused(
    const float* __restrict__ qg, const float* __restrict__ kg,
    const float* __restrict__ vg, float* __restrict__ og) {
  __shared__ unsigned short K_lds[KVBLK * D_DIM];
  __shared__ unsigned short VT_lds[D_DIM * KVBLK];
  __shared__ unsigned short P_lds[4][16 * KVBLK];

  const int tid = threadIdx.x;
  const int lane = tid & 63;
  const int wid = tid >> 6;
  const int l15 = lane & 15;
  const int lg = lane >> 4;

  const int bid = blockIdx.x;
  const int bh = (bid & 7) | ((bid >> 7) << 3);
  const int qt = (bid >> 3) & 15;

  const size_t base = (size_t)bh * (S_LEN * D_DIM);
  const int qw = qt * 64 + wid * 16;

  short8 qf[4];
  {
    const float* qp = qg + base + (size_t)(qw + l15) * D_DIM + lg * 8;
    #pragma unroll
    for (int c = 0; c < 4; ++c) {
      float4 a = *(const float4*)(qp + c * 32);
      float4 b = *(const float4*)(qp + c * 32 + 4);
      const float s = 0.0078125f;
      a.x *= s; a.y *= s; a.z *= s; a.w *= s;
      b.x *= s; b.y *= s; b.z *= s; b.w *= s;
      qf[c] = pack8(a, b);
    }
  }

  float m_r[4], l_r[4];
  f32x4 o_acc[8];
  #pragma unroll
  for (int r = 0; r < 4; ++r) { m_r[r] = -INFINITY; l_r[r] = 0.f; }
  #pragma unroll
  for (int dt = 0; dt < 8; ++dt) o_acc[dt] = (f32x4){0.f, 0.f, 0.f, 0.f};

  for (int kv0 = 0; kv0 < S_LEN; kv0 += KVBLK) {
    {
      const float* kb = kg + base + (size_t)kv0 * D_DIM;
      #pragma unroll
      for (int c = tid; c < KVBLK * D_DIM / 8; c += 256) {
        int row = c >> 4, dc = c & 15;
        const float* p = kb + row * D_DIM + dc * 8;
        float4 a = *(const float4*)p;
        float4 b = *(const float4*)(p + 4);
        int sidx = row * 128 + ((dc * 8) ^ ((row & 7) << 3));
        *(short8*)&K_lds[sidx] = pack8(a, b);
      }
    }
    {
      const float* vb = vg + base + (size_t)kv0 * D_DIM;
      #pragma unroll
      for (int u = tid; u < (KVBLK / 4) * (D_DIM / 4); u += 256) {
        int ib = u & 15;
        int db = u >> 4;
        const float* p = vb + (ib * 4) * D_DIM + db * 4;
        float rr[4][4];
        #pragma unroll
        for (int c = 0; c < 4; ++c) {
          float4 t = *(const float4*)(p + c * D_DIM);
          rr[c][0] = t.x; rr[c][1] = t.y; rr[c][2] = t.z; rr[c][3] = t.w;
        }
        #pragma unroll
        for (int j = 0; j < 4; ++j) {
          short4v w;
          w[0] = (short)f2bf(rr[0][j]); w[1] = (short)f2bf(rr[1][j]);
          w[2] = (short)f2bf(rr[2][j]); w[3] = (short)f2bf(rr[3][j]);
          int row = db * 4 + j;
          int sidx = row * 64 + ((ib * 4) ^ ((row & 7) << 3));
          *(short4v*)&VT_lds[sidx] = w;
        }
      }
    }
    __syncthreads();

    f32x4 sacc[4];
    #pragma unroll
    for (int tc = 0; tc < 4; ++tc) sacc[tc] = (f32x4){0.f, 0.f, 0.f, 0.f};
    #pragma unroll
    for (int tc = 0; tc < 4; ++tc) {
      int row = tc * 16 + l15;
      #pragma unroll
      for (int ck = 0; ck < 4; ++ck) {
        int sidx = row * 128 + ((ck * 32 + lg * 8) ^ ((row & 7) << 3));
        short8 kf = *(const short8*)&K_lds[sidx];
        sacc[tc] = __builtin_amdgcn_mfma_f32_16x16x32_bf16(qf[ck], kf, sacc[tc], 0, 0, 0);
      }
    }

    float alpha[4], ps[4];
    #pragma unroll
    for (int r = 0; r < 4; ++r) {
      float a = fmaxf(fmaxf(sacc[0][r], sacc[1][r]), fmaxf(sacc[2][r], sacc[3][r]));
      a = fmaxf(a, __shfl_xor(a, 1));
      a = fmaxf(a, __shfl_xor(a, 2));
      a = fmaxf(a, __shfl_xor(a, 4));
      a = fmaxf(a, __shfl_xor(a, 8));
      float mn = fmaxf(m_r[r], a);
      alpha[r] = __expf(m_r[r] - mn);
      m_r[r] = mn;
      ps[r] = 0.f;
    }
    #pragma unroll
    for (int tc = 0; tc < 4; ++tc) {
      #pragma unroll
      for (int r = 0; r < 4; ++r) {
        float p = __expf(sacc[tc][r] - m_r[r]);
        ps[r] += p;
        int prow = lg * 4 + r;
        int pcol = tc * 16 + l15;
        P_lds[wid][prow * 64 + (pcol ^ ((prow & 7) << 3))] = f2bf(p);
      }
    }
    #pragma unroll
    for (int r = 0; r < 4; ++r) {
      float s = ps[r];
      s += __shfl_xor(s, 1); s += __shfl_xor(s, 2);
      s += __shfl_xor(s, 4); s += __shfl_xor(s, 8);
      l_r[r] = l_r[r] * alpha[r] + s;
    }
    #pragma unroll
    for (int dt = 0; dt < 8; ++dt) {
      #pragma unroll
      for (int r = 0; r < 4; ++r) o_acc[dt][r] *= alpha[r];
    }

    #pragma unroll
    for (int kc = 0; kc < 2; ++kc) {
      int pidx = l15 * 64 + ((kc * 32 + lg * 8) ^ ((l15 & 7) << 3));
      short8 pf = *(const short8*)&P_lds[wid][pidx];
      #pragma unroll
      for (int dt = 0; dt < 8; ++dt) {
        int vrow = dt * 16 + l15;
        int vidx = vrow * 64 + ((kc * 32 + lg * 8) ^ ((vrow & 7) << 3));
        short8 vf = *(const short8*)&VT_lds[vidx];
        o_acc[dt] = __builtin_amdgcn_mfma_f32_16x16x32_bf16(pf, vf, o_acc[dt], 0, 0, 0);
      }
    }
    __syncthreads();
  }

  #pragma unroll
  for (int r = 0; r < 4; ++r) {
    float inv = 1.0f / l_r[r];
    float* op = og + base + (size_t)(qw + lg * 4 + r) * D_DIM + l15;
    #pragma unroll
    for (int dt = 0; dt < 8; ++dt) op[dt * 16] = o_acc[dt][r] * inv;
  }
}

extern "C" void kernel_launch(void* const* d_in, const int* in_sizes, int n_in,
                              void* d_out, int out_size, void* d_ws, size_t ws_size,
                              hipStream_t stream) {
  const float* q = (const float*)d_in[0];
  const float* k = (const float*)d_in[1];
  const float* v = (const float*)d_in[2];
  float* o = (float*)d_out;

  const size_t n_elem = (size_t)BH_N * S_LEN * D_DIM;
  const size_t need = 2 * n_elem * sizeof(unsigned short);

  if (ws_size >= need) {
    unsigned short* kbf = (unsigned short*)d_ws;
    unsigned short* vtbf = kbf + n_elem;
    conv_k<<<dim3(2048), dim3(256), 0, stream>>>(k, kbf, (int)(n_elem / 8));
    conv_vt<<<dim3(4096), dim3(256), 0, stream>>>(v, vtbf);
    attn_main<<<dim3(1024), dim3(512), 0, stream>>>(q, kbf, vtbf, o);
  } else {
    attn_fused<<<dim3(2048), dim3(256), 0, stream>>>(q, k, v, o);
  }
}

// Round 4
// 136.558 us; speedup vs baseline: 2.2473x; 1.1364x over previous
//
#include <hip/hip_runtime.h>

#define S_LEN 1024
#define D_DIM 128
#define KVBLK 64
#define QROWS_BLK 128  // 8 waves * 16 q-rows
#define BH_N 128
#define M0_LOG2 2.0f   // fixed softmax base (log2 domain); |score*log2e| < 1 << 2

typedef __attribute__((ext_vector_type(8))) short short8;
typedef __attribute__((ext_vector_type(4))) short short4v;
typedef __attribute__((ext_vector_type(4))) float f32x4;

__device__ __forceinline__ unsigned short f2bf(float f) {
  union { float f; unsigned u; } x; x.f = f;
  unsigned r = x.u + 0x7fffu + ((x.u >> 16) & 1u);
  return (unsigned short)(r >> 16);
}

__device__ __forceinline__ short8 pack8(float4 a, float4 b) {
  short8 f;
  f[0] = (short)f2bf(a.x); f[1] = (short)f2bf(a.y);
  f[2] = (short)f2bf(a.z); f[3] = (short)f2bf(a.w);
  f[4] = (short)f2bf(b.x); f[5] = (short)f2bf(b.y);
  f[6] = (short)f2bf(b.z); f[7] = (short)f2bf(b.w);
  return f;
}

__device__ __forceinline__ void gload_lds16(const void* g, void* l) {
  __builtin_amdgcn_global_load_lds(
      (const __attribute__((address_space(1))) unsigned int*)g,
      (__attribute__((address_space(3))) unsigned int*)l, 16, 0, 0);
}

// ---------- prepass 1: K f32 -> bf16 row-major ----------
__global__ __launch_bounds__(256) void conv_k(const float* __restrict__ in,
                                              unsigned short* __restrict__ out,
                                              int n8) {
  int i = blockIdx.x * 256 + threadIdx.x;
  int stride = gridDim.x * 256;
  for (; i < n8; i += stride) {
    float4 a = ((const float4*)in)[i * 2];
    float4 b = ((const float4*)in)[i * 2 + 1];
    ((short8*)out)[i] = pack8(a, b);
  }
}

// ---------- prepass 2: V f32 [bh][s][d] -> bf16 VT [bh][d][s] ----------
__global__ __launch_bounds__(256) void conv_vt(const float* __restrict__ v,
                                               unsigned short* __restrict__ vt) {
  __shared__ unsigned short tile[64][72];
  int b = blockIdx.x;  // 128 bh * 16 s-tiles * 2 d-tiles = 4096
  int d0 = (b & 1) * 64;
  int s0 = ((b >> 1) & 15) * 64;
  int bh = b >> 5;
  int t = threadIdx.x;
  #pragma unroll
  for (int i = 0; i < 4; ++i) {
    int s = (t >> 4) + i * 16;
    int dl = (t & 15) * 4;
    float4 x = *(const float4*)(v + ((size_t)(bh * S_LEN) + s0 + s) * D_DIM + d0 + dl);
    tile[s][dl + 0] = f2bf(x.x); tile[s][dl + 1] = f2bf(x.y);
    tile[s][dl + 2] = f2bf(x.z); tile[s][dl + 3] = f2bf(x.w);
  }
  __syncthreads();
  #pragma unroll
  for (int i = 0; i < 2; ++i) {
    int j = i * 256 + t;
    int dl = j >> 3, sc = j & 7;
    short8 w;
    #pragma unroll
    for (int q = 0; q < 8; ++q) w[q] = (short)tile[sc * 8 + q][dl];
    *(short8*)(vt + ((size_t)(bh * D_DIM) + d0 + dl) * S_LEN + s0 + sc * 8) = w;
  }
}

// ---------- main attention (swapped QK^T, T12-lite P path) ----------
__global__ __launch_bounds__(512, 4) void attn_main(
    const float* __restrict__ qg, const unsigned short* __restrict__ kbf,
    const unsigned short* __restrict__ vtbf, float* __restrict__ og) {
  __shared__ unsigned short K_lds[2][KVBLK * D_DIM];   // 2 x 16 KB
  __shared__ unsigned short VT_lds[2][D_DIM * KVBLK];  // 2 x 16 KB
  __shared__ unsigned short P_lds[8][16 * KVBLK];      // 16 KB

  const int tid = threadIdx.x;
  const int lane = tid & 63;
  const int wid = tid >> 6;
  const int l15 = lane & 15;
  const int lg = lane >> 4;

  const int bid = blockIdx.x;
  const int bh = (bid & 7) | ((bid >> 6) << 3);
  const int qt = (bid >> 3) & 7;

  const size_t base = (size_t)bh * (S_LEN * D_DIM);
  const int qw = qt * QROWS_BLK + wid * 16;

  // Q fragments, pre-scaled by log2(e)/128
  short8 qf[4];
  {
    const float* qp = qg + base + (size_t)(qw + l15) * D_DIM + lg * 8;
    const float s = 0.0078125f * 1.44269504088896f;
    #pragma unroll
    for (int c = 0; c < 4; ++c) {
      float4 a = *(const float4*)(qp + c * 32);
      float4 b = *(const float4*)(qp + c * 32 + 4);
      a.x *= s; a.y *= s; a.z *= s; a.w *= s;
      b.x *= s; b.y *= s; b.z *= s; b.w *= s;
      qf[c] = pack8(a, b);
    }
  }

  // Per-lane softmax state: this lane's q-row is qw + l15 (all 4 lg copies partial)
  float neg_m = -M0_LOG2;  // -m in log2 domain, folded into MFMA acc init
  float l_r = 0.f;         // partial sum over this lane's k-subset
  f32x4 o_acc[8];
  #pragma unroll
  for (int dt = 0; dt < 8; ++dt) o_acc[dt] = (f32x4){0.f, 0.f, 0.f, 0.f};

  const unsigned short* kb = kbf + (size_t)bh * (S_LEN * D_DIM);
  const unsigned short* vtb = vtbf + (size_t)bh * (D_DIM * S_LEN);

  #define STAGE(buf, kv0)                                                      \
    {                                                                          \
      _Pragma("unroll")                                                        \
      for (int i = 0; i < 2; ++i) {                                            \
        int row = wid * 8 + i * 4 + (lane >> 4);                               \
        int c = lane & 15;                                                     \
        const unsigned short* src =                                            \
            kb + (size_t)((kv0) + row) * D_DIM + ((c ^ (row & 7)) * 8);        \
        gload_lds16(src, &K_lds[buf][(wid * 8 + i * 4) * D_DIM]);              \
      }                                                                        \
      _Pragma("unroll")                                                        \
      for (int i = 0; i < 2; ++i) {                                            \
        int drow = wid * 16 + i * 8 + (lane >> 3);                             \
        int c = lane & 7;                                                      \
        const unsigned short* src =                                            \
            vtb + (size_t)drow * S_LEN + (kv0) + ((c ^ (drow & 7)) * 8);       \
        gload_lds16(src, &VT_lds[buf][(wid * 16 + i * 8) * KVBLK]);            \
      }                                                                        \
    }

  STAGE(0, 0);
  __syncthreads();

  char* const pwave = (char*)&P_lds[wid][0];

  #pragma unroll 2
  for (int t = 0; t < S_LEN / KVBLK; ++t) {
    const int cur = t & 1;
    if (t + 1 < S_LEN / KVBLK) STAGE(cur ^ 1, (t + 1) * KVBLK);

    // ---- swapped QK^T: sacc = K_tile * Q^T -> lane holds S[k][q=l15] ----
    // D col = l15 = q-row; D row (lg*4+r) = local k; global k = tc*16+lg*4+r.
    f32x4 sacc[4];
    #pragma unroll
    for (int tc = 0; tc < 4; ++tc) sacc[tc] = (f32x4){neg_m, neg_m, neg_m, neg_m};
    #pragma unroll
    for (int tc = 0; tc < 4; ++tc) {
      int row = tc * 16 + l15;
      #pragma unroll
      for (int ck = 0; ck < 4; ++ck) {
        int sidx = row * 128 + ((ck * 32 + lg * 8) ^ ((row & 7) << 3));
        short8 kf = *(const short8*)&K_lds[cur][sidx];
        sacc[tc] = __builtin_amdgcn_mfma_f32_16x16x32_bf16(kf, qf[ck], sacc[tc], 0, 0, 0);
      }
    }

    // ---- guard: escalate to exact online softmax if any score exceeds m ----
    float lmax = sacc[0][0];
    #pragma unroll
    for (int tc = 0; tc < 4; ++tc) {
      #pragma unroll
      for (int r = 0; r < 4; ++r) lmax = fmaxf(lmax, sacc[tc][r]);
    }
    if (__any(lmax > 0.f)) {  // never taken for bounded scores; exact fallback
      float a = lmax;
      a = fmaxf(a, __shfl_xor(a, 16));
      a = fmaxf(a, __shfl_xor(a, 32));   // full row max for row q=l15
      float delta = fmaxf(a, 0.f);
      neg_m -= delta;
      l_r *= exp2f(-delta);
      float ar[4];
      #pragma unroll
      for (int r = 0; r < 4; ++r)
        ar[r] = exp2f(-__shfl(delta, lg * 4 + r, 16));  // delta of row lg*4+r
      #pragma unroll
      for (int dt = 0; dt < 8; ++dt) {
        #pragma unroll
        for (int r = 0; r < 4; ++r) o_acc[dt][r] *= ar[r];
      }
      #pragma unroll
      for (int tc = 0; tc < 4; ++tc) {
        #pragma unroll
        for (int r = 0; r < 4; ++r) sacc[tc][r] -= delta;
      }
    }

    // ---- p = exp2(sacc); lane-local l; packed P write (cvt_pk + b64) ----
    #pragma unroll
    for (int tc = 0; tc < 4; ++tc) {
      float p0 = exp2f(sacc[tc][0]);
      float p1 = exp2f(sacc[tc][1]);
      float p2 = exp2f(sacc[tc][2]);
      float p3 = exp2f(sacc[tc][3]);
      l_r += (p0 + p1) + (p2 + p3);
      unsigned w0, w1;
      asm("v_cvt_pk_bf16_f32 %0, %1, %2" : "=v"(w0) : "v"(p0), "v"(p1));
      asm("v_cvt_pk_bf16_f32 %0, %1, %2" : "=v"(w1) : "v"(p2), "v"(p3));
      // P[q = l15][k = tc*16 + lg*4 .. +4], row-XOR swizzled
      int pb = l15 * 128 + ((tc * 32 + lg * 8) ^ ((l15 & 7) << 4));
      *(uint2*)(pwave + pb) = make_uint2(w0, w1);
    }

    // ---- PV: O[16q][128d] += P[16][64] * V[64][128] ----
    #pragma unroll
    for (int kc = 0; kc < 2; ++kc) {
      int pbr = l15 * 128 + ((kc * 64 + lg * 16) ^ ((l15 & 7) << 4));
      short8 pf = *(const short8*)(pwave + pbr);
      #pragma unroll
      for (int dt = 0; dt < 8; ++dt) {
        int vrow = dt * 16 + l15;
        int vidx = vrow * 64 + ((kc * 32 + lg * 8) ^ ((vrow & 7) << 3));
        short8 vf = *(const short8*)&VT_lds[cur][vidx];
        o_acc[dt] = __builtin_amdgcn_mfma_f32_16x16x32_bf16(pf, vf, o_acc[dt], 0, 0, 0);
      }
    }
    __syncthreads();
  }

  // ---- deferred l reduction + epilogue ----
  float lsum = l_r;
  lsum += __shfl_xor(lsum, 16);
  lsum += __shfl_xor(lsum, 32);      // full denom for row q = l15
  float linv = 1.0f / lsum;
  float lr[4];
  #pragma unroll
  for (int r = 0; r < 4; ++r) lr[r] = __shfl(linv, lg * 4 + r, 16);
  #pragma unroll
  for (int r = 0; r < 4; ++r) {
    float* op = og + base + (size_t)(qw + lg * 4 + r) * D_DIM + l15;
    #pragma unroll
    for (int dt = 0; dt < 8; ++dt) op[dt * 16] = o_acc[dt][r] * lr[r];
  }
}

// ---------- fallback (fused, f32 inputs) if ws too small ----------
__global__ __launch_bounds__(256) void attn_fused(
    const float* __restrict__ qg, const float* __restrict__ kg,
    const float* __restrict__ vg, float* __restrict__ og) {
  __shared__ unsigned short K_lds[KVBLK * D_DIM];
  __shared__ unsigned short VT_lds[D_DIM * KVBLK];
  __shared__ unsigned short P_lds[4][16 * KVBLK];

  const int tid = threadIdx.x;
  const int lane = tid & 63;
  const int wid = tid >> 6;
  const int l15 = lane & 15;
  const int lg = lane >> 4;

  const int bid = blockIdx.x;
  const int bh = (bid & 7) | ((bid >> 7) << 3);
  const int qt = (bid >> 3) & 15;

  const size_t base = (size_t)bh * (S_LEN * D_DIM);
  const int qw = qt * 64 + wid * 16;

  short8 qf[4];
  {
    const float* qp = qg + base + (size_t)(qw + l15) * D_DIM + lg * 8;
    #pragma unroll
    for (int c = 0; c < 4; ++c) {
      float4 a = *(const float4*)(qp + c * 32);
      float4 b = *(const float4*)(qp + c * 32 + 4);
      const float s = 0.0078125f;
      a.x *= s; a.y *= s; a.z *= s; a.w *= s;
      b.x *= s; b.y *= s; b.z *= s; b.w *= s;
      qf[c] = pack8(a, b);
    }
  }

  float m_r[4], l_r[4];
  f32x4 o_acc[8];
  #pragma unroll
  for (int r = 0; r < 4; ++r) { m_r[r] = -INFINITY; l_r[r] = 0.f; }
  #pragma unroll
  for (int dt = 0; dt < 8; ++dt) o_acc[dt] = (f32x4){0.f, 0.f, 0.f, 0.f};

  for (int kv0 = 0; kv0 < S_LEN; kv0 += KVBLK) {
    {
      const float* kb = kg + base + (size_t)kv0 * D_DIM;
      #pragma unroll
      for (int c = tid; c < KVBLK * D_DIM / 8; c += 256) {
        int row = c >> 4, dc = c & 15;
        const float* p = kb + row * D_DIM + dc * 8;
        float4 a = *(const float4*)p;
        float4 b = *(const float4*)(p + 4);
        int sidx = row * 128 + ((dc * 8) ^ ((row & 7) << 3));
        *(short8*)&K_lds[sidx] = pack8(a, b);
      }
    }
    {
      const float* vb = vg + base + (size_t)kv0 * D_DIM;
      #pragma unroll
      for (int u = tid; u < (KVBLK / 4) * (D_DIM / 4); u += 256) {
        int ib = u & 15;
        int db = u >> 4;
        const float* p = vb + (ib * 4) * D_DIM + db * 4;
        float rr[4][4];
        #pragma unroll
        for (int c = 0; c < 4; ++c) {
          float4 t = *(const float4*)(p + c * D_DIM);
          rr[c][0] = t.x; rr[c][1] = t.y; rr[c][2] = t.z; rr[c][3] = t.w;
        }
        #pragma unroll
        for (int j = 0; j < 4; ++j) {
          short4v w;
          w[0] = (short)f2bf(rr[0][j]); w[1] = (short)f2bf(rr[1][j]);
          w[2] = (short)f2bf(rr[2][j]); w[3] = (short)f2bf(rr[3][j]);
          int row = db * 4 + j;
          int sidx = row * 64 + ((ib * 4) ^ ((row & 7) << 3));
          *(short4v*)&VT_lds[sidx] = w;
        }
      }
    }
    __syncthreads();

    f32x4 sacc[4];
    #pragma unroll
    for (int tc = 0; tc < 4; ++tc) sacc[tc] = (f32x4){0.f, 0.f, 0.f, 0.f};
    #pragma unroll
    for (int tc = 0; tc < 4; ++tc) {
      int row = tc * 16 + l15;
      #pragma unroll
      for (int ck = 0; ck < 4; ++ck) {
        int sidx = row * 128 + ((ck * 32 + lg * 8) ^ ((row & 7) << 3));
        short8 kf = *(const short8*)&K_lds[sidx];
        sacc[tc] = __builtin_amdgcn_mfma_f32_16x16x32_bf16(qf[ck], kf, sacc[tc], 0, 0, 0);
      }
    }

    float alpha[4], ps[4];
    #pragma unroll
    for (int r = 0; r < 4; ++r) {
      float a = fmaxf(fmaxf(sacc[0][r], sacc[1][r]), fmaxf(sacc[2][r], sacc[3][r]));
      a = fmaxf(a, __shfl_xor(a, 1));
      a = fmaxf(a, __shfl_xor(a, 2));
      a = fmaxf(a, __shfl_xor(a, 4));
      a = fmaxf(a, __shfl_xor(a, 8));
      float mn = fmaxf(m_r[r], a);
      alpha[r] = __expf(m_r[r] - mn);
      m_r[r] = mn;
      ps[r] = 0.f;
    }
    #pragma unroll
    for (int tc = 0; tc < 4; ++tc) {
      #pragma unroll
      for (int r = 0; r < 4; ++r) {
        float p = __expf(sacc[tc][r] - m_r[r]);
        ps[r] += p;
        int prow = lg * 4 + r;
        int pcol = tc * 16 + l15;
        P_lds[wid][prow * 64 + (pcol ^ ((prow & 7) << 3))] = f2bf(p);
      }
    }
    #pragma unroll
    for (int r = 0; r < 4; ++r) {
      float s = ps[r];
      s += __shfl_xor(s, 1); s += __shfl_xor(s, 2);
      s += __shfl_xor(s, 4); s += __shfl_xor(s, 8);
      l_r[r] = l_r[r] * alpha[r] + s;
    }
    #pragma unroll
    for (int dt = 0; dt < 8; ++dt) {
      #pragma unroll
      for (int r = 0; r < 4; ++r) o_acc[dt][r] *= alpha[r];
    }

    #pragma unroll
    for (int kc = 0; kc < 2; ++kc) {
      int pidx = l15 * 64 + ((kc * 32 + lg * 8) ^ ((l15 & 7) << 3));
      short8 pf = *(const short8*)&P_lds[wid][pidx];
      #pragma unroll
      for (int dt = 0; dt < 8; ++dt) {
        int vrow = dt * 16 + l15;
        int vidx = vrow * 64 + ((kc * 32 + lg * 8) ^ ((vrow & 7) << 3));
        short8 vf = *(const short8*)&VT_lds[vidx];
        o_acc[dt] = __builtin_amdgcn_mfma_f32_16x16x32_bf16(pf, vf, o_acc[dt], 0, 0, 0);
      }
    }
    __syncthreads();
  }

  #pragma unroll
  for (int r = 0; r < 4; ++r) {
    float inv = 1.0f / l_r[r];
    float* op = og + base + (size_t)(qw + lg * 4 + r) * D_DIM + l15;
    #pragma unroll
    for (int dt = 0; dt < 8; ++dt) op[dt * 16] = o_acc[dt][r] * inv;
  }
}

extern "C" void kernel_launch(void* const* d_in, const int* in_sizes, int n_in,
                              void* d_out, int out_size, void* d_ws, size_t ws_size,
                              hipStream_t stream) {
  const float* q = (const float*)d_in[0];
  const float* k = (const float*)d_in[1];
  const float* v = (const float*)d_in[2];
  float* o = (float*)d_out;

  const size_t n_elem = (size_t)BH_N * S_LEN * D_DIM;
  const size_t need = 2 * n_elem * sizeof(unsigned short);

  if (ws_size >= need) {
    unsigned short* kbf = (unsigned short*)d_ws;
    unsigned short* vtbf = kbf + n_elem;
    conv_k<<<dim3(2048), dim3(256), 0, stream>>>(k, kbf, (int)(n_elem / 8));
    conv_vt<<<dim3(4096), dim3(256), 0, stream>>>(v, vtbf);
    attn_main<<<dim3(1024), dim3(512), 0, stream>>>(q, kbf, vtbf, o);
  } else {
    attn_fused<<<dim3(2048), dim3(256), 0, stream>>>(q, k, v, o);
  }
}